// Round 10
// baseline (978.178 us; speedup 1.0000x reference)
//
#include <hip/hip_runtime.h>
#include <float.h>

// MAM dense, fused. C[m,n] = max_k(A[m,k]*W[n,k]) + min_k + bias[n] + arg
// indices (numpy first-occurrence).
//
// R9 lesson: any 16B-aligned LDS row stride gives b128 gathers only 8
// distinct 4-bank windows (stride mod 32 = multiple of 4) -> ~8-way
// conflicts for random rows. Fixes here:
//  - Rescan layout [row][33] (odd float stride): bank = (ml+k) mod 32,
//    conflict-free b32 gathers. Descending-k equality scan, two chains
//    (even/odd k) + min to break the cndmask dependency chain.
//  - Main staging as k-PAIR float2 [16][66]: writes are ds_write_b64
//    (~2-way, half the instrs of R9's 4-way b32 scatter); reads 2x b128
//    per array; (k,k+1) products land in adjacent regs -> v_pk_mul_f32
//    eligible: inner loop = pk_mul + max3 + min3 per 2 products.

typedef float v2f __attribute__((ext_vector_type(2)));

#define BM 64
#define BN 64
#define BK 32
#define KP 16     // k-pairs per chunk
#define LDPP 66   // main staging [KP][LDPP] float2 (pad 64->66, 2-way banks)
#define LDP2 33   // rescan [64][LDP2] float, odd stride -> conflict-free b32
#define NCHUNK 32
#define NENT (BM * BN * 2)

__global__ __launch_bounds__(256)
void mam_fused(const float* __restrict__ A, const float* __restrict__ W,
               const float* __restrict__ bias,
               float* __restrict__ out_v, float* __restrict__ out_ax,
               float* __restrict__ out_an, int M, int N, int K) {
  // aliased pool: main Alsp[16][66]f2 (8448B) + Wlsp @8448 (ends 16896B)
  //               rescan As2[64][33]f (8448B) + Ws2 @8448 (ends 16896B)
  __shared__ __align__(16) unsigned char pool[16896];
  float2(*Alsp)[LDPP] = (float2(*)[LDPP])pool;
  float2(*Wlsp)[LDPP] = (float2(*)[LDPP])(pool + KP * LDPP * 8);
  float(*As2)[LDP2] = (float(*)[LDP2])pool;
  float(*Ws2)[LDP2] = (float(*)[LDP2])(pool + 64 * LDP2 * 4);
  __shared__ unsigned short ents[NENT];
  __shared__ float tgt[8192];  // [side][ml*64+nl], 32 KB
  __shared__ unsigned cnt[NCHUNK];
  __shared__ unsigned off[NCHUNK + 1];

  const int tid = threadIdx.x;
  const int tx = tid & 15;
  const int ty = tid >> 4;
  const int m0 = blockIdx.y * BM;
  const int n0 = blockIdx.x * BN;

  float vmax[4][4], vmin[4][4];
  int cmax[4][4], cmin[4][4];
#pragma unroll
  for (int i = 0; i < 4; ++i)
#pragma unroll
    for (int j = 0; j < 4; ++j) {
      vmax[i][j] = -FLT_MAX;
      vmin[i][j] = FLT_MAX;
      cmax[i][j] = 0;
      cmin[i][j] = 0;
    }

  const int r = tid >> 3;  // 0..31
  const int c8 = tid & 7;  // 0..7

  const int nchunk = K / BK;
  for (int ch = 0; ch < nchunk; ++ch) {
    const int kk = ch * BK;
    // stage chunk as k-pairs: Alsp[kp][row] = (A[row][2kp], A[row][2kp+1])
#pragma unroll
    for (int rr = 0; rr < 2; ++rr) {
      const int row = r + rr * 32;
      int gm = m0 + row; gm = gm < M ? gm : M - 1;
      const float4 va = *(const float4*)(A + (size_t)gm * K + kk + c8 * 4);
      Alsp[c8 * 2 + 0][row] = make_float2(va.x, va.y);
      Alsp[c8 * 2 + 1][row] = make_float2(va.z, va.w);
      int gn = n0 + row; gn = gn < N ? gn : N - 1;
      const float4 vw = *(const float4*)(W + (size_t)gn * K + kk + c8 * 4);
      Wlsp[c8 * 2 + 0][row] = make_float2(vw.x, vw.y);
      Wlsp[c8 * 2 + 1][row] = make_float2(vw.z, vw.w);
    }
    __syncthreads();

    float tmax[4][4], tmin[4][4];
#pragma unroll
    for (int i = 0; i < 4; ++i)
#pragma unroll
      for (int j = 0; j < 4; ++j) { tmax[i][j] = -FLT_MAX; tmin[i][j] = FLT_MAX; }

#pragma unroll
    for (int kp = 0; kp < KP; ++kp) {
      const float4 ta0 = *(const float4*)&Alsp[kp][ty * 4];      // m0,m1 pairs
      const float4 ta1 = *(const float4*)&Alsp[kp][ty * 4 + 2];  // m2,m3 pairs
      const float4 tw0 = *(const float4*)&Wlsp[kp][tx * 4];
      const float4 tw1 = *(const float4*)&Wlsp[kp][tx * 4 + 2];
      v2f a2[4], w2[4];
      a2[0] = (v2f){ta0.x, ta0.y}; a2[1] = (v2f){ta0.z, ta0.w};
      a2[2] = (v2f){ta1.x, ta1.y}; a2[3] = (v2f){ta1.z, ta1.w};
      w2[0] = (v2f){tw0.x, tw0.y}; w2[1] = (v2f){tw0.z, tw0.w};
      w2[2] = (v2f){tw1.x, tw1.y}; w2[3] = (v2f){tw1.z, tw1.w};
#pragma unroll
      for (int i = 0; i < 4; ++i)
#pragma unroll
        for (int j = 0; j < 4; ++j) {
          const v2f p = a2[i] * w2[j];               // v_pk_mul_f32
          tmax[i][j] = fmaxf(tmax[i][j], fmaxf(p.x, p.y));  // v_max3_f32
          tmin[i][j] = fminf(tmin[i][j], fminf(p.x, p.y));  // v_min3_f32
        }
    }

#pragma unroll
    for (int i = 0; i < 4; ++i)
#pragma unroll
      for (int j = 0; j < 4; ++j) {
        if (tmax[i][j] > vmax[i][j]) { vmax[i][j] = tmax[i][j]; cmax[i][j] = ch; }
        if (tmin[i][j] < vmin[i][j]) { vmin[i][j] = tmin[i][j]; cmin[i][j] = ch; }
      }
    __syncthreads();
  }

  // ---- value output + park targets in LDS ----
  const int gn = n0 + tx * 4;
  float4 bv = make_float4(0.f, 0.f, 0.f, 0.f);
  if (gn + 3 < N) bv = *(const float4*)(bias + gn);
#pragma unroll
  for (int i = 0; i < 4; ++i) {
    const int gm = m0 + ty * 4 + i;
    if (gm < M && gn + 3 < N) {
      const size_t base = (size_t)gm * N + gn;
      float4 o;
      o.x = vmax[i][0] + vmin[i][0] + bv.x;
      o.y = vmax[i][1] + vmin[i][1] + bv.y;
      o.z = vmax[i][2] + vmin[i][2] + bv.z;
      o.w = vmax[i][3] + vmin[i][3] + bv.w;
      *(float4*)(out_v + base) = o;
    }
#pragma unroll
    for (int j = 0; j < 4; ++j) {
      const int idx = (ty * 4 + i) * 64 + tx * 4 + j;
      tgt[idx] = vmax[i][j];         // side 0
      tgt[4096 + idx] = vmin[i][j];  // side 1
    }
  }

  // ---- bucket entries by chunk (side rides in the entry) ----
  if (tid < NCHUNK) cnt[tid] = 0;
  __syncthreads();
#pragma unroll
  for (int i = 0; i < 4; ++i)
#pragma unroll
    for (int j = 0; j < 4; ++j) {
      atomicAdd(&cnt[cmax[i][j]], 1u);
      atomicAdd(&cnt[cmin[i][j]], 1u);
    }
  __syncthreads();
  if (tid == 0) {
    unsigned s = 0;
    for (int b = 0; b < NCHUNK; ++b) { off[b] = s; s += cnt[b]; }
    off[NCHUNK] = s;
  }
  __syncthreads();
  if (tid < NCHUNK) cnt[tid] = off[tid];
  __syncthreads();
#pragma unroll
  for (int i = 0; i < 4; ++i)
#pragma unroll
    for (int j = 0; j < 4; ++j) {
      const unsigned enc = (unsigned)((ty * 4 + i) * 64 + (tx * 4 + j));
      unsigned p1 = atomicAdd(&cnt[cmax[i][j]], 1u);
      ents[p1] = (unsigned short)enc;               // side 0
      unsigned p2 = atomicAdd(&cnt[cmin[i][j]], 1u);
      ents[p2] = (unsigned short)(enc | 0x1000u);   // side 1
    }

  // ---- per-chunk rescan: first k with product == target ----
  const int row2 = tid >> 2;  // 0..63
  const int q2 = tid & 3;     // 0..3
  const size_t MN = (size_t)M * N;

  for (int ch = 0; ch < nchunk; ++ch) {
    const int kk = ch * BK;
    __syncthreads();  // prior readers (and bucketing/targets) done
    {
      int gm = m0 + row2; gm = gm < M ? gm : M - 1;
      const float* ar = A + (size_t)gm * K + kk;
      const float4 a0 = *(const float4*)(ar + q2 * 4);
      const float4 a1 = *(const float4*)(ar + q2 * 4 + 16);
      As2[row2][q2 * 4 + 0] = a0.x;
      As2[row2][q2 * 4 + 1] = a0.y;
      As2[row2][q2 * 4 + 2] = a0.z;
      As2[row2][q2 * 4 + 3] = a0.w;
      As2[row2][q2 * 4 + 16] = a1.x;
      As2[row2][q2 * 4 + 17] = a1.y;
      As2[row2][q2 * 4 + 18] = a1.z;
      As2[row2][q2 * 4 + 19] = a1.w;
      int gnr = n0 + row2; gnr = gnr < N ? gnr : N - 1;
      const float* wr = W + (size_t)gnr * K + kk;
      const float4 w0 = *(const float4*)(wr + q2 * 4);
      const float4 w1 = *(const float4*)(wr + q2 * 4 + 16);
      Ws2[row2][q2 * 4 + 0] = w0.x;
      Ws2[row2][q2 * 4 + 1] = w0.y;
      Ws2[row2][q2 * 4 + 2] = w0.z;
      Ws2[row2][q2 * 4 + 3] = w0.w;
      Ws2[row2][q2 * 4 + 16] = w1.x;
      Ws2[row2][q2 * 4 + 17] = w1.y;
      Ws2[row2][q2 * 4 + 18] = w1.z;
      Ws2[row2][q2 * 4 + 19] = w1.w;
    }
    __syncthreads();

    const int lo = off[ch], hi = off[ch + 1];
    for (int e = lo + tid; e < hi; e += 256) {
      const int enc = ents[e];
      const int side = enc >> 12;
      const int ml = (enc >> 6) & 63;
      const int nl = enc & 63;
      const float t = tgt[side * 4096 + (enc & 0xFFF)];
      int pe = 0x7FFF, po = 0x7FFF;  // two chains: even/odd k
#pragma unroll
      for (int g = KP - 1; g >= 0; --g) {  // descending: last write = min k
        const float a0 = As2[ml][2 * g + 0];
        const float a1 = As2[ml][2 * g + 1];
        const float w0 = Ws2[nl][2 * g + 0];
        const float w1 = Ws2[nl][2 * g + 1];
        pe = (a0 * w0 == t) ? 2 * g : pe;
        po = (a1 * w1 == t) ? 2 * g + 1 : po;
      }
      const int pos = pe < po ? pe : po;  // smallest matching k
      const int gm = m0 + ml, gnn = n0 + nl;
      if (gm < M && gnn < N) {
        float* outp = out_ax + (size_t)side * MN;  // out_an = out_ax + MN
        outp[(size_t)gm * N + gnn] = (float)(kk + pos);
      }
    }
  }
}

extern "C" void kernel_launch(void* const* d_in, const int* in_sizes, int n_in,
                              void* d_out, int out_size, void* d_ws, size_t ws_size,
                              hipStream_t stream) {
  const float* A = (const float*)d_in[0];     // [M, K] fp32
  const float* W = (const float*)d_in[1];     // [N, K] fp32
  const float* bias = (const float*)d_in[2];  // [N]    fp32
  const int N = in_sizes[2];
  const int K = in_sizes[1] / N;
  const int M = in_sizes[0] / K;
  float* out_v = (float*)d_out;
  float* out_ax = out_v + (size_t)M * N;
  float* out_an = out_v + 2 * (size_t)M * N;
  dim3 grid((N + BN - 1) / BN, (M + BM - 1) / BM);
  mam_fused<<<grid, dim3(256), 0, stream>>>(A, W, bias, out_v, out_ax, out_an,
                                            M, N, K);
}